// Round 8
// baseline (380.779 us; speedup 1.0000x reference)
//
#include <hip/hip_runtime.h>
#include <hip/hip_bf16.h>
#include <hip/hip_cooperative_groups.h>
#include <math.h>

namespace cg = cooperative_groups;

#define BB 64
#define SS 2048
#define HH 512
#define VV 50257
#define KD 1024    // I + H
#define NSPLIT 32  // attn s-chunks per batch row
#define NTILE 786  // ceil(VV/64)
#define LCH 8      // fallback lsm chunks per row
#define LPT 25     // fallback lsm elems/thread

typedef float f32x4 __attribute__((ext_vector_type(4)));
typedef __bf16 bf16x8 __attribute__((ext_vector_type(8)));

__device__ __forceinline__ float dot4(float4 a, float4 b) {
  return a.x*b.x + a.y*b.y + a.z*b.z + a.w*b.w;
}

__device__ __forceinline__ bf16x8 cvt8(float4 a, float4 b) {
  bf16x8 r;
  r[0]=(__bf16)a.x; r[1]=(__bf16)a.y; r[2]=(__bf16)a.z; r[3]=(__bf16)a.w;
  r[4]=(__bf16)b.x; r[5]=(__bf16)b.y; r[6]=(__bf16)b.z; r[7]=(__bf16)b.w;
  return r;
}

// featA fragment-linear layout: element (b, k) lives at
//   (k>>5)*2048 + (b>>4)*512 + ((k>>3)&3)*128 + (b&15)*8 + (k&7)
__device__ __forceinline__ size_t fragAddr(int b, int k) {
  return (size_t)(k >> 5)*2048 + (size_t)(b >> 4)*512
       + (size_t)((k >> 3) & 3)*128 + (size_t)(b & 15)*8 + (size_t)(k & 7);
}

// ===========================================================================
// Cooperative mega-kernel. Grid-size-agnostic (all phases grid-stride).
// ===========================================================================
__global__ __launch_bounds__(256, 2) void decoder_mega(
    const int* __restrict__ last_out, const float* __restrict__ hprev,
    const float* __restrict__ enc, const float* __restrict__ emb,
    const float* __restrict__ W_ih, const float* __restrict__ b_ih,
    const float* __restrict__ W_hh, const float* __restrict__ b_hh,
    const float* __restrict__ W_out, const float* __restrict__ b_out,
    float* __restrict__ out, __hip_bfloat16* __restrict__ featA,
    float* __restrict__ gates, float* __restrict__ pacc,
    float* __restrict__ pm, float* __restrict__ pl,
    float* __restrict__ pmE, float* __restrict__ plE,
    float* __restrict__ cvec)
{
  cg::grid_group grid = cg::this_grid();
  __shared__ float smem[64*65];   // 16.6 KB, aliased across phases

  const int bid = blockIdx.x;
  const int nb  = gridDim.x;
  const int t = threadIdx.x;
  const int w = t >> 6, lane = t & 63;

  // ============ Phase A: attention partials (2048 recs, grid-stride) =======
#pragma unroll 1
  for (int rec = bid; rec < BB*NSPLIT; rec += nb) {
    const int b = rec >> 5, split = rec & 31;
    const float* hb = hprev + b*HH + lane*8;
    const float4 h0 = *(const float4*)hb;
    const float4 h1 = *(const float4*)(hb + 4);

    float m = -INFINITY, lsum = 0.f;
    float acc8[8];
#pragma unroll
    for (int j = 0; j < 8; ++j) acc8[j] = 0.f;

    const int s0 = split*64 + w*16;
    float4 ca[4], cb[4];
#pragma unroll
    for (int i = 0; i < 4; ++i) {
      const float* ep = enc + ((size_t)(s0 + i)*BB + b)*HH + lane*8;
      ca[i] = *(const float4*)ep; cb[i] = *(const float4*)(ep + 4);
    }
#pragma unroll 1
    for (int g = 0; g < 4; ++g) {
      float4 na[4], nb4[4];
      if (g < 3) {
#pragma unroll
        for (int i = 0; i < 4; ++i) {
          const float* ep = enc + ((size_t)(s0 + (g+1)*4 + i)*BB + b)*HH + lane*8;
          na[i] = *(const float4*)ep; nb4[i] = *(const float4*)(ep + 4);
        }
      }
      float d0 = dot4(h0,ca[0]) + dot4(h1,cb[0]);
      float d1 = dot4(h0,ca[1]) + dot4(h1,cb[1]);
      float d2 = dot4(h0,ca[2]) + dot4(h1,cb[2]);
      float d3 = dot4(h0,ca[3]) + dot4(h1,cb[3]);
#pragma unroll
      for (int off = 32; off >= 1; off >>= 1) {
        d0 += __shfl_xor(d0, off, 64);
        d1 += __shfl_xor(d1, off, 64);
        d2 += __shfl_xor(d2, off, 64);
        d3 += __shfl_xor(d3, off, 64);
      }
      const float gm = fmaxf(fmaxf(d0,d1), fmaxf(d2,d3));
      const float mn = fmaxf(m, gm);
      const float sc = __expf(m - mn);
      const float p0 = __expf(d0 - mn), p1 = __expf(d1 - mn);
      const float p2 = __expf(d2 - mn), p3 = __expf(d3 - mn);
      lsum = lsum*sc + ((p0+p1) + (p2+p3));
      acc8[0] = acc8[0]*sc + p0*ca[0].x + p1*ca[1].x + p2*ca[2].x + p3*ca[3].x;
      acc8[1] = acc8[1]*sc + p0*ca[0].y + p1*ca[1].y + p2*ca[2].y + p3*ca[3].y;
      acc8[2] = acc8[2]*sc + p0*ca[0].z + p1*ca[1].z + p2*ca[2].z + p3*ca[3].z;
      acc8[3] = acc8[3]*sc + p0*ca[0].w + p1*ca[1].w + p2*ca[2].w + p3*ca[3].w;
      acc8[4] = acc8[4]*sc + p0*cb[0].x + p1*cb[1].x + p2*cb[2].x + p3*cb[3].x;
      acc8[5] = acc8[5]*sc + p0*cb[0].y + p1*cb[1].y + p2*cb[2].y + p3*cb[3].y;
      acc8[6] = acc8[6]*sc + p0*cb[0].z + p1*cb[1].z + p2*cb[2].z + p3*cb[3].z;
      acc8[7] = acc8[7]*sc + p0*cb[0].w + p1*cb[1].w + p2*cb[2].w + p3*cb[3].w;
      m = mn;
      if (g < 3) {
#pragma unroll
        for (int i = 0; i < 4; ++i) { ca[i] = na[i]; cb[i] = nb4[i]; }
      }
    }

    float* sm4 = smem; float* sl4 = smem + 4; float* sacc = smem + 8;
    if (lane == 0) { sm4[w] = m; sl4[w] = lsum; }
    __syncthreads();
    const float M = fmaxf(fmaxf(sm4[0], sm4[1]), fmaxf(sm4[2], sm4[3]));
    const float ew = __expf(m - M);
#pragma unroll
    for (int j = 0; j < 8; ++j) sacc[w*HH + lane*8 + j] = acc8[j]*ew;
    __syncthreads();
    for (int hh = t; hh < HH; hh += 256)
      pacc[(size_t)rec*HH + hh] = sacc[0*HH+hh]+sacc[1*HH+hh]+sacc[2*HH+hh]+sacc[3*HH+hh];
    if (t == 0) {
      float L = sl4[0]*__expf(sm4[0]-M) + sl4[1]*__expf(sm4[1]-M)
              + sl4[2]*__expf(sm4[2]-M) + sl4[3]*__expf(sm4[3]-M);
      pm[rec] = M; pl[rec] = L;
    }
    __syncthreads();   // WAR guard before next rec reuses smem
  }
  grid.sync();

  // ============ Phase B: attention reduce -> context -> featA ==============
#pragma unroll 1
  for (int b = bid; b < BB; b += nb) {
    float* smm = smem; float* sll = smem + 32; float* sco = smem + 64;
    if (t < NSPLIT) { smm[t] = pm[b*NSPLIT + t]; sll[t] = pl[b*NSPLIT + t]; }
    __syncthreads();
    float M = -INFINITY;
    for (int q = 0; q < NSPLIT; ++q) M = fmaxf(M, smm[q]);
    float L = 0.f;
    for (int q = 0; q < NSPLIT; ++q) L += sll[q]*__expf(smm[q]-M);
    const float inv = 1.f/L;
    if (t < NSPLIT) sco[t] = __expf(smm[t]-M)*inv;
    __syncthreads();
    const int hh0 = 2*t;
    float s0 = 0.f, s1 = 0.f;
    for (int q = 0; q < NSPLIT; ++q) {
      const float* pq = pacc + ((size_t)b*NSPLIT + q)*HH;
      s0 += pq[hh0]   * sco[q];
      s1 += pq[hh0+1] * sco[q];
    }
    const size_t a = fragAddr(b, HH + hh0);
    featA[a]   = (__hip_bfloat16)s0;
    featA[a+1] = (__hip_bfloat16)s1;
    __syncthreads();   // WAR guard
  }
  grid.sync();

  // ============ Phase C: GRU gates GEMM (72 units, grid-stride) ============
#pragma unroll 1
  for (int u = bid; u < 72; u += nb) {
    const int gt = u / 3, seg = u % 3;
    const int col = lane & 15, kg = lane >> 4;
    const int g = gt*64 + w*16 + col;
    const float* wrow = (seg == 2) ? (W_hh + (size_t)g*HH)
                                   : (W_ih + (size_t)g*KD + seg*HH);
    int lo_r[4];
#pragma unroll
    for (int mt = 0; mt < 4; ++mt) lo_r[mt] = last_out[mt*16 + col];

    f32x4 acc[4];
#pragma unroll
    for (int mt = 0; mt < 4; ++mt) acc[mt] = (f32x4){0.f,0.f,0.f,0.f};

    for (int k0 = 0; k0 < HH; k0 += 32) {
      const float* wp = wrow + k0 + kg*8;
      const bf16x8 bf = cvt8(*(const float4*)wp, *(const float4*)(wp+4));
#pragma unroll
      for (int mt = 0; mt < 4; ++mt) {
        const int bb = mt*16 + col;
        bf16x8 af;
        if (seg == 0) {
          const float* ap = emb + (size_t)lo_r[mt]*HH + k0 + kg*8;
          af = cvt8(*(const float4*)ap, *(const float4*)(ap+4));
        } else if (seg == 1) {
          af = *(const bf16x8*)(featA + fragAddr(bb, HH + k0 + kg*8));
        } else {
          const float* ap = hprev + (size_t)bb*HH + k0 + kg*8;
          af = cvt8(*(const float4*)ap, *(const float4*)(ap+4));
        }
        acc[mt] = __builtin_amdgcn_mfma_f32_16x16x32_bf16(af, bf, acc[mt], 0, 0, 0);
      }
    }
    float* gp = gates + (size_t)seg*BB*1536;
#pragma unroll
    for (int mt = 0; mt < 4; ++mt)
#pragma unroll
      for (int reg = 0; reg < 4; ++reg) {
        const int brow = mt*16 + kg*4 + reg;
        gp[(size_t)brow*1536 + g] = acc[mt][reg];
      }
  }
  grid.sync();

  // ============ Phase D: GRU pointwise (128 units, grid-stride) ============
#pragma unroll 1
  for (int u = bid; u < 128; u += nb) {
    const int b = u >> 1;
    const int j = (u & 1)*256 + t;
    const float* g0 = gates + (size_t)b*1536;
    const float* g1 = gates + (size_t)(BB + b)*1536;
    const float* g2 = gates + (size_t)(2*BB + b)*1536;
    const float i_r = g0[j]        + g1[j];
    const float i_z = g0[HH + j]   + g1[HH + j];
    const float i_n = g0[2*HH + j] + g1[2*HH + j];
    const float r = 1.f/(1.f + __expf(-(i_r + g2[j] + b_ih[j] + b_hh[j])));
    const float z = 1.f/(1.f + __expf(-(i_z + g2[HH+j] + b_ih[HH+j] + b_hh[HH+j])));
    const float n = tanhf(i_n + b_ih[2*HH+j] + r*(g2[2*HH+j] + b_hh[2*HH+j]));
    const float hp = hprev[b*HH + j];
    const float hn = (1.f - z)*n + z*hp;
    out[(size_t)BB*VV + b*HH + j] = hn;           // hidden output
    featA[fragAddr(b, j)] = (__hip_bfloat16)hn;
  }
  grid.sync();

  // ============ Phase E: logits GEMM (+bias) -> out, lsm tile partials =====
#pragma unroll 1
  for (int tile = bid; tile < NTILE; tile += nb) {
    const int col = lane & 15, kg = lane >> 4;
    const int v = tile*64 + w*16 + col;
    const int vc = (v < VV) ? v : (VV - 1);
    const float* wp = W_out + (size_t)vc*KD + kg*8;
    const __hip_bfloat16* fp = featA + lane*8;

    f32x4 acc[4];
#pragma unroll
    for (int mt = 0; mt < 4; ++mt) acc[mt] = (f32x4){0.f,0.f,0.f,0.f};

    float4 wa = *(const float4*)(wp);
    float4 wb = *(const float4*)(wp + 4);
    bf16x8 a0 = *(const bf16x8*)(fp);
    bf16x8 a1 = *(const bf16x8*)(fp + 512);
    bf16x8 a2 = *(const bf16x8*)(fp + 1024);
    bf16x8 a3 = *(const bf16x8*)(fp + 1536);

    for (int k0 = 0; k0 < KD; k0 += 32) {
      const int kn = (k0 + 32 < KD) ? (k0 + 32) : 0;
      const float4 nwa = *(const float4*)(wp + kn);
      const float4 nwb = *(const float4*)(wp + kn + 4);
      const __hip_bfloat16* fn = fp + (kn >> 5)*2048;
      const bf16x8 n0 = *(const bf16x8*)(fn);
      const bf16x8 n1 = *(const bf16x8*)(fn + 512);
      const bf16x8 n2 = *(const bf16x8*)(fn + 1024);
      const bf16x8 n3 = *(const bf16x8*)(fn + 1536);

      const bf16x8 bf = cvt8(wa, wb);
      acc[0] = __builtin_amdgcn_mfma_f32_16x16x32_bf16(a0, bf, acc[0], 0, 0, 0);
      acc[1] = __builtin_amdgcn_mfma_f32_16x16x32_bf16(a1, bf, acc[1], 0, 0, 0);
      acc[2] = __builtin_amdgcn_mfma_f32_16x16x32_bf16(a2, bf, acc[2], 0, 0, 0);
      acc[3] = __builtin_amdgcn_mfma_f32_16x16x32_bf16(a3, bf, acc[3], 0, 0, 0);

      wa = nwa; wb = nwb; a0 = n0; a1 = n1; a2 = n2; a3 = n3;
    }

    const float bo = (v < VV) ? b_out[v] : 0.f;
#pragma unroll
    for (int mt = 0; mt < 4; ++mt)
#pragma unroll
      for (int reg = 0; reg < 4; ++reg) {
        const float val = acc[mt][reg] + bo;
        const int brow = mt*16 + kg*4 + reg;
        if (v < VV) out[(size_t)brow*VV + v] = val;
        smem[brow*65 + w*16 + col] = (v < VV) ? val : -INFINITY;
      }
    __syncthreads();
    if (t < 64) {
      float M = -INFINITY;
#pragma unroll 8
      for (int i = 0; i < 64; ++i) M = fmaxf(M, smem[t*65 + i]);
      float L = 0.f;
#pragma unroll 8
      for (int i = 0; i < 64; ++i) L += __expf(smem[t*65 + i] - M);
      pmE[t*1024 + tile] = M; plE[t*1024 + tile] = L;
    }
    __syncthreads();
  }
  grid.sync();

  // ============ Phase F: reduce lsm partials -> cvec[row] (wave/row) =======
#pragma unroll 1
  for (int row = bid*4 + w; row < BB; row += nb*4) {
    float M = -INFINITY, L = 0.f;
    for (int q = lane; q < NTILE; q += 64) {
      const float mq = pmE[row*1024 + q], lq = plE[row*1024 + q];
      const float mn = fmaxf(M, mq);
      L = L*__expf(M - mn) + lq*__expf(mq - mn);
      M = mn;
    }
#pragma unroll
    for (int off = 32; off >= 1; off >>= 1) {
      const float m2 = __shfl_xor(M, off, 64), l2 = __shfl_xor(L, off, 64);
      const float mn = fmaxf(M, m2);
      L = L*__expf(M - mn) + l2*__expf(m2 - mn);
      M = mn;
    }
    if (lane == 0) cvec[row] = M + logf(L);
  }
  grid.sync();

  // ============ Phase G: logits -= cvec[row] ===============================
  const unsigned total4 = (unsigned)(BB*VV/4u);   // 804112 exactly
  for (unsigned idx = bid*256u + t; idx < total4; idx += (unsigned)nb*256u) {
    const unsigned i = idx*4u;
    float4 v = *(float4*)(out + i);
    v.x -= cvec[i/VV];
    v.y -= cvec[(i+1)/VV];
    v.z -= cvec[(i+2)/VV];
    v.w -= cvec[(i+3)/VV];
    *(float4*)(out + i) = v;
  }
}

// ===========================================================================
// Fallback path: the proven R6 7-kernel pipeline (195 us).
// ===========================================================================
__global__ __launch_bounds__(256) void attn_partial(
    const float* __restrict__ hprev, const float* __restrict__ enc,
    float* __restrict__ pm, float* __restrict__ pl, float* __restrict__ pacc)
{
  const int b = blockIdx.x >> 5;
  const int split = blockIdx.x & 31;
  const int t = threadIdx.x;
  const int w = t >> 6, lane = t & 63;

  const float* hb = hprev + b*HH + lane*8;
  const float4 h0 = *(const float4*)hb;
  const float4 h1 = *(const float4*)(hb + 4);

  float m = -INFINITY, lsum = 0.f;
  float acc[8];
#pragma unroll
  for (int j = 0; j < 8; ++j) acc[j] = 0.f;

  const int s0 = split*64 + w*16;
#pragma unroll 1
  for (int g = 0; g < 4; ++g) {
    const float* ep0 = enc + ((size_t)(s0 + g*4 + 0)*BB + b)*HH + lane*8;
    const float* ep1 = enc + ((size_t)(s0 + g*4 + 1)*BB + b)*HH + lane*8;
    const float* ep2 = enc + ((size_t)(s0 + g*4 + 2)*BB + b)*HH + lane*8;
    const float* ep3 = enc + ((size_t)(s0 + g*4 + 3)*BB + b)*HH + lane*8;
    const float4 e0a = *(const float4*)ep0, e0b = *(const float4*)(ep0+4);
    const float4 e1a = *(const float4*)ep1, e1b = *(const float4*)(ep1+4);
    const float4 e2a = *(const float4*)ep2, e2b = *(const float4*)(ep2+4);
    const float4 e3a = *(const float4*)ep3, e3b = *(const float4*)(ep3+4);

    float d0 = dot4(h0,e0a) + dot4(h1,e0b);
    float d1 = dot4(h0,e1a) + dot4(h1,e1b);
    float d2 = dot4(h0,e2a) + dot4(h1,e2b);
    float d3 = dot4(h0,e3a) + dot4(h1,e3b);
#pragma unroll
    for (int off = 32; off >= 1; off >>= 1) {
      d0 += __shfl_xor(d0, off, 64);
      d1 += __shfl_xor(d1, off, 64);
      d2 += __shfl_xor(d2, off, 64);
      d3 += __shfl_xor(d3, off, 64);
    }
    const float gm = fmaxf(fmaxf(d0,d1), fmaxf(d2,d3));
    const float mn = fmaxf(m, gm);
    const float sc = __expf(m - mn);
    const float p0 = __expf(d0 - mn), p1 = __expf(d1 - mn);
    const float p2 = __expf(d2 - mn), p3 = __expf(d3 - mn);
    lsum = lsum*sc + ((p0+p1) + (p2+p3));
    acc[0] = acc[0]*sc + p0*e0a.x + p1*e1a.x + p2*e2a.x + p3*e3a.x;
    acc[1] = acc[1]*sc + p0*e0a.y + p1*e1a.y + p2*e2a.y + p3*e3a.y;
    acc[2] = acc[2]*sc + p0*e0a.z + p1*e1a.z + p2*e2a.z + p3*e3a.z;
    acc[3] = acc[3]*sc + p0*e0a.w + p1*e1a.w + p2*e2a.w + p3*e3a.w;
    acc[4] = acc[4]*sc + p0*e0b.x + p1*e1b.x + p2*e2b.x + p3*e3b.x;
    acc[5] = acc[5]*sc + p0*e0b.y + p1*e1b.y + p2*e2b.y + p3*e3b.y;
    acc[6] = acc[6]*sc + p0*e0b.z + p1*e1b.z + p2*e2b.z + p3*e3b.z;
    acc[7] = acc[7]*sc + p0*e0b.w + p1*e1b.w + p2*e2b.w + p3*e3b.w;
    m = mn;
  }

  __shared__ float sm4[4], sl4[4];
  __shared__ float sacc[4][HH];
  if (lane == 0) { sm4[w] = m; sl4[w] = lsum; }
  __syncthreads();
  const float M = fmaxf(fmaxf(sm4[0], sm4[1]), fmaxf(sm4[2], sm4[3]));
  const float ew = __expf(m - M);
#pragma unroll
  for (int j = 0; j < 8; ++j) sacc[w][lane*8 + j] = acc[j]*ew;
  __syncthreads();

  const int rec = blockIdx.x;
  for (int hh = t; hh < HH; hh += 256)
    pacc[(size_t)rec*HH + hh] = sacc[0][hh]+sacc[1][hh]+sacc[2][hh]+sacc[3][hh];
  if (t == 0) {
    float L = sl4[0]*__expf(sm4[0]-M) + sl4[1]*__expf(sm4[1]-M)
            + sl4[2]*__expf(sm4[2]-M) + sl4[3]*__expf(sm4[3]-M);
    pm[rec] = M; pl[rec] = L;
  }
}

__global__ __launch_bounds__(256) void attn_reduce(
    const float* __restrict__ pm, const float* __restrict__ pl,
    const float* __restrict__ pacc, __hip_bfloat16* __restrict__ featA)
{
  const int b = blockIdx.x, t = threadIdx.x;
  __shared__ float smm[NSPLIT], sll[NSPLIT], sco[NSPLIT];
  if (t < NSPLIT) { smm[t] = pm[b*NSPLIT + t]; sll[t] = pl[b*NSPLIT + t]; }
  __syncthreads();
  float M = -INFINITY;
  for (int q = 0; q < NSPLIT; ++q) M = fmaxf(M, smm[q]);
  float L = 0.f;
  for (int q = 0; q < NSPLIT; ++q) L += sll[q]*__expf(smm[q]-M);
  const float inv = 1.f/L;
  if (t < NSPLIT) sco[t] = __expf(smm[t]-M)*inv;
  __syncthreads();
  const int hh0 = 2*t;
  float s0 = 0.f, s1 = 0.f;
  for (int q = 0; q < NSPLIT; ++q) {
    const float* pq = pacc + ((size_t)b*NSPLIT + q)*HH;
    s0 += pq[hh0]   * sco[q];
    s1 += pq[hh0+1] * sco[q];
  }
  const size_t a = fragAddr(b, HH + hh0);
  featA[a]   = (__hip_bfloat16)s0;
  featA[a+1] = (__hip_bfloat16)s1;
}

__global__ __launch_bounds__(256) void gru_gemm(
    const int* __restrict__ last_out, const float* __restrict__ emb,
    const float* __restrict__ hprev, const __hip_bfloat16* __restrict__ featA,
    const float* __restrict__ W_ih, const float* __restrict__ W_hh,
    float* __restrict__ gates)
{
  const int gt  = blockIdx.x / 3;
  const int seg = blockIdx.x % 3;
  const int w = threadIdx.x >> 6, lane = threadIdx.x & 63;
  const int col = lane & 15, kg = lane >> 4;
  const int g = gt*64 + w*16 + col;

  const float* wrow = (seg == 2) ? (W_hh + (size_t)g*HH)
                                 : (W_ih + (size_t)g*KD + seg*HH);
  int lo_r[4];
#pragma unroll
  for (int mt = 0; mt < 4; ++mt) lo_r[mt] = last_out[mt*16 + col];

  f32x4 acc[4];
#pragma unroll
  for (int mt = 0; mt < 4; ++mt) acc[mt] = (f32x4){0.f,0.f,0.f,0.f};

  for (int k0 = 0; k0 < HH; k0 += 32) {
    const float* wp = wrow + k0 + kg*8;
    const bf16x8 bf = cvt8(*(const float4*)wp, *(const float4*)(wp+4));
#pragma unroll
    for (int mt = 0; mt < 4; ++mt) {
      const int bb = mt*16 + col;
      bf16x8 af;
      if (seg == 0) {
        const float* ap = emb + (size_t)lo_r[mt]*HH + k0 + kg*8;
        af = cvt8(*(const float4*)ap, *(const float4*)(ap+4));
      } else if (seg == 1) {
        af = *(const bf16x8*)(featA + fragAddr(bb, HH + k0 + kg*8));
      } else {
        const float* ap = hprev + (size_t)bb*HH + k0 + kg*8;
        af = cvt8(*(const float4*)ap, *(const float4*)(ap+4));
      }
      acc[mt] = __builtin_amdgcn_mfma_f32_16x16x32_bf16(af, bf, acc[mt], 0, 0, 0);
    }
  }

  float* gp = gates + (size_t)seg*BB*1536;
#pragma unroll
  for (int mt = 0; mt < 4; ++mt)
#pragma unroll
    for (int reg = 0; reg < 4; ++reg) {
      const int brow = mt*16 + kg*4 + reg;
      gp[(size_t)brow*1536 + g] = acc[mt][reg];
    }
}

__global__ __launch_bounds__(512) void gru_pointwise(
    const float* __restrict__ gates, const float* __restrict__ hprev,
    const float* __restrict__ b_ih, const float* __restrict__ b_hh,
    float* __restrict__ hid_out, __hip_bfloat16* __restrict__ featA)
{
  const int b = blockIdx.x, j = threadIdx.x;
  const float* g0 = gates + (size_t)b*1536;
  const float* g1 = gates + (size_t)(BB + b)*1536;
  const float* g2 = gates + (size_t)(2*BB + b)*1536;

  const float i_r = g0[j]        + g1[j];
  const float i_z = g0[HH + j]   + g1[HH + j];
  const float i_n = g0[2*HH + j] + g1[2*HH + j];

  const float r = 1.f/(1.f + __expf(-(i_r + g2[j] + b_ih[j] + b_hh[j])));
  const float z = 1.f/(1.f + __expf(-(i_z + g2[HH+j] + b_ih[HH+j] + b_hh[HH+j])));
  const float n = tanhf(i_n + b_ih[2*HH+j] + r*(g2[2*HH+j] + b_hh[2*HH+j]));
  const float hp = hprev[b*HH + j];
  const float hn = (1.f - z)*n + z*hp;
  hid_out[b*HH + j] = hn;
  featA[fragAddr(b, j)] = (__hip_bfloat16)hn;
}

__global__ __launch_bounds__(256) void logits_gemm(
    const __hip_bfloat16* __restrict__ featA, const float* __restrict__ W_out,
    const float* __restrict__ b_out, float* __restrict__ out)
{
  const int w = threadIdx.x >> 6, lane = threadIdx.x & 63;
  const int col = lane & 15, kg = lane >> 4;
  const int v = blockIdx.x*64 + w*16 + col;
  const int vc = (v < VV) ? v : (VV - 1);

  const float* wp = W_out + (size_t)vc*KD + kg*8;
  const __hip_bfloat16* fp = featA + lane*8;

  f32x4 acc[4];
#pragma unroll
  for (int mt = 0; mt < 4; ++mt) acc[mt] = (f32x4){0.f,0.f,0.f,0.f};

  float4 wa = *(const float4*)(wp);
  float4 wb = *(const float4*)(wp + 4);
  bf16x8 a0 = *(const bf16x8*)(fp);
  bf16x8 a1 = *(const bf16x8*)(fp + 512);
  bf16x8 a2 = *(const bf16x8*)(fp + 1024);
  bf16x8 a3 = *(const bf16x8*)(fp + 1536);

  for (int k0 = 0; k0 < KD; k0 += 32) {
    const int kn = (k0 + 32 < KD) ? (k0 + 32) : 0;
    const float4 nwa = *(const float4*)(wp + kn);
    const float4 nwb = *(const float4*)(wp + kn + 4);
    const __hip_bfloat16* fn = fp + (kn >> 5)*2048;
    const bf16x8 n0 = *(const bf16x8*)(fn);
    const bf16x8 n1 = *(const bf16x8*)(fn + 512);
    const bf16x8 n2 = *(const bf16x8*)(fn + 1024);
    const bf16x8 n3 = *(const bf16x8*)(fn + 1536);

    const bf16x8 bf = cvt8(wa, wb);
    acc[0] = __builtin_amdgcn_mfma_f32_16x16x32_bf16(a0, bf, acc[0], 0, 0, 0);
    acc[1] = __builtin_amdgcn_mfma_f32_16x16x32_bf16(a1, bf, acc[1], 0, 0, 0);
    acc[2] = __builtin_amdgcn_mfma_f32_16x16x32_bf16(a2, bf, acc[2], 0, 0, 0);
    acc[3] = __builtin_amdgcn_mfma_f32_16x16x32_bf16(a3, bf, acc[3], 0, 0, 0);

    wa = nwa; wb = nwb; a0 = n0; a1 = n1; a2 = n2; a3 = n3;
  }

  if (v < VV) {
    const float bo = b_out[v];
#pragma unroll
    for (int mt = 0; mt < 4; ++mt)
#pragma unroll
      for (int reg = 0; reg < 4; ++reg) {
        const int brow = mt*16 + kg*4 + reg;
        out[(size_t)brow*VV + v] = acc[mt][reg] + bo;
      }
  }
}

__global__ __launch_bounds__(256) void lsm_partial(
    const float* __restrict__ out, float* __restrict__ pm2, float* __restrict__ pl2)
{
  const int b = blockIdx.x >> 3, ch = blockIdx.x & (LCH-1);
  const int t = threadIdx.x;
  const float* p = out + (size_t)b*VV;
  const int beg = ch*(256*LPT);

  float r[LPT];
#pragma unroll
  for (int i = 0; i < LPT; ++i) {
    const int idx = beg + t + i*256;
    r[i] = (idx < VV) ? p[idx] : -INFINITY;
  }
  float m = r[0];
#pragma unroll
  for (int i = 1; i < LPT; ++i) m = fmaxf(m, r[i]);
  float l = 0.f;
#pragma unroll
  for (int i = 0; i < LPT; ++i) l += __expf(r[i] - m);

#pragma unroll
  for (int off = 32; off >= 1; off >>= 1) {
    const float m2 = __shfl_xor(m, off, 64), l2 = __shfl_xor(l, off, 64);
    const float mn = fmaxf(m, m2);
    l = l*__expf(m - mn) + l2*__expf(m2 - mn);
    m = mn;
  }
  __shared__ float sm[4], sl[4];
  const int w = t >> 6, lane = t & 63;
  if (lane == 0) { sm[w] = m; sl[w] = l; }
  __syncthreads();
  if (t == 0) {
    float M = sm[0], L = sl[0];
#pragma unroll
    for (int q = 1; q < 4; ++q) {
      const float mn = fmaxf(M, sm[q]);
      L = L*__expf(M - mn) + sl[q]*__expf(sm[q] - mn);
      M = mn;
    }
    pm2[blockIdx.x] = M; pl2[blockIdx.x] = L;
  }
}

__global__ __launch_bounds__(256) void lsm_sub(
    float* __restrict__ out, const float* __restrict__ pm2,
    const float* __restrict__ pl2)
{
  const int t = threadIdx.x;
  const size_t off = (size_t)blockIdx.x * 1024;
  const size_t total = (size_t)BB*VV;
  __shared__ float cs[2];
  __shared__ int rowA_s;
  if (t < 2) {
    size_t pos = (t == 0) ? off : (off + 1023 < total ? off + 1023 : total - 1);
    const int row = (int)(pos / VV);
    float M = -INFINITY, L = 0.f;
#pragma unroll
    for (int q = 0; q < LCH; ++q) {
      const float mq = pm2[row*LCH + q], lq = pl2[row*LCH + q];
      const float mn = fmaxf(M, mq);
      L = L*__expf(M - mn) + lq*__expf(mq - mn);
      M = mn;
    }
    cs[t] = M + logf(L);
    if (t == 0) rowA_s = row;
  }
  __syncthreads();

  const size_t i = off + (size_t)t*4;
  if (i >= total) return;
  const size_t rs = (size_t)(rowA_s + 1)*VV;
  float4 v = *(float4*)(out + i);
  v.x -= (i     >= rs) ? cs[1] : cs[0];
  v.y -= (i + 1 >= rs) ? cs[1] : cs[0];
  v.z -= (i + 2 >= rs) ? cs[1] : cs[0];
  v.w -= (i + 3 >= rs) ? cs[1] : cs[0];
  *(float4*)(out + i) = v;
}

// ---------------------------------------------------------------------------
extern "C" void kernel_launch(void* const* d_in, const int* in_sizes, int n_in,
                              void* d_out, int out_size, void* d_ws, size_t ws_size,
                              hipStream_t stream)
{
  const int*   last_output = (const int*)d_in[0];
  const float* last_hidden = (const float*)d_in[1];
  const float* enc         = (const float*)d_in[2];
  const float* emb         = (const float*)d_in[3];
  const float* W_ih        = (const float*)d_in[4];
  const float* b_ih        = (const float*)d_in[5];
  const float* W_hh        = (const float*)d_in[6];
  const float* b_hh        = (const float*)d_in[7];
  const float* W_out       = (const float*)d_in[8];
  const float* b_out       = (const float*)d_in[9];
  float* out = (float*)d_out;

  // ws layout (~1.9 MB)
  __hip_bfloat16* featA = (__hip_bfloat16*)d_ws;            // 128 KB
  float* gates = (float*)((char*)d_ws + 131072);            // 1.18 MB
  float* pm   = gates + (size_t)3*BB*1536;                  // 2048
  float* pl   = pm + BB*NSPLIT;                             // 2048
  float* pm2  = pl + BB*NSPLIT;                             // 512
  float* pl2  = pm2 + BB*LCH;                               // 512
  float* pmE  = pl2 + BB*LCH;                               // 64*1024
  float* plE  = pmE + BB*1024;                              // 64*1024
  float* cvec = plE + BB*1024;                              // 64
  float* pacc = out;   // 4 MB parked in dead logits region (both paths)
  float* hid_out = out + (size_t)BB*VV;

  // --- try the cooperative mega-kernel ---
  int maxb = 0;
  hipError_t qe = hipOccupancyMaxActiveBlocksPerMultiprocessor(&maxb, decoder_mega, 256, 0);
  int grid = (qe == hipSuccess) ? maxb * 256 : 0;
  if (grid > 1024) grid = 1024;
  bool done = false;
  if (grid >= 256) {
    void* args[] = {
      (void*)&last_output, (void*)&last_hidden, (void*)&enc, (void*)&emb,
      (void*)&W_ih, (void*)&b_ih, (void*)&W_hh, (void*)&b_hh,
      (void*)&W_out, (void*)&b_out, (void*)&out, (void*)&featA,
      (void*)&gates, (void*)&pacc, (void*)&pm, (void*)&pl,
      (void*)&pmE, (void*)&plE, (void*)&cvec
    };
    hipError_t le = hipLaunchCooperativeKernel(decoder_mega, dim3(grid), dim3(256),
                                               args, 0, stream);
    done = (le == hipSuccess);
  }
  if (done) return;

  // --- fallback: proven 7-kernel pipeline ---
  attn_partial <<<dim3(BB*NSPLIT), dim3(256), 0, stream>>>(last_hidden, enc, pm, pl, pacc);
  attn_reduce  <<<dim3(BB),        dim3(256), 0, stream>>>(pm, pl, pacc, featA);
  gru_gemm     <<<dim3(24*3),      dim3(256), 0, stream>>>(last_output, emb, last_hidden,
                                                           featA, W_ih, W_hh, gates);
  gru_pointwise<<<dim3(BB),        dim3(512), 0, stream>>>(gates, last_hidden, b_ih, b_hh,
                                                           hid_out, featA);
  logits_gemm  <<<dim3((VV+63)/64), dim3(256), 0, stream>>>(featA, W_out, b_out, out);
  lsm_partial  <<<dim3(BB*LCH),    dim3(256), 0, stream>>>(out, pm2, pl2);
  lsm_sub      <<<dim3((int)(((size_t)BB*VV + 1023)/1024)), dim3(256), 0, stream>>>(out, pm2, pl2);
}

// Round 9
// 229.193 us; speedup vs baseline: 1.6614x; 1.6614x over previous
//
#include <hip/hip_runtime.h>
#include <hip/hip_bf16.h>
#include <math.h>

#define BB 64
#define SS 2048
#define HH 512
#define VV 50257
#define KD 1024    // I + H
#define NSPLIT 32  // attn s-chunks per batch row
#define NTILE 786  // ceil(VV/64)

typedef float f32x4 __attribute__((ext_vector_type(4)));
typedef __bf16 bf16x8 __attribute__((ext_vector_type(8)));

__device__ __forceinline__ float dot4(float4 a, float4 b) {
  return a.x*b.x + a.y*b.y + a.z*b.z + a.w*b.w;
}

__device__ __forceinline__ bf16x8 cvt8(float4 a, float4 b) {
  bf16x8 r;
  r[0]=(__bf16)a.x; r[1]=(__bf16)a.y; r[2]=(__bf16)a.z; r[3]=(__bf16)a.w;
  r[4]=(__bf16)b.x; r[5]=(__bf16)b.y; r[6]=(__bf16)b.z; r[7]=(__bf16)b.w;
  return r;
}

// featA fragment-linear layout: element (b, k) lives at
//   (k>>5)*2048 + (b>>4)*512 + ((k>>3)&3)*128 + (b&15)*8 + (k&7)
__device__ __forceinline__ size_t fragAddr(int b, int k) {
  return (size_t)(k >> 5)*2048 + (size_t)(b >> 4)*512
       + (size_t)((k >> 3) & 3)*128 + (size_t)(b & 15)*8 + (size_t)(k & 7);
}

// ---------------------------------------------------------------------------
// Kernel A: attention partials, TWO-PASS (no online rescale -> no serial
// group->group dependency). Pass 1: all 16 scores, 8-wide independent
// butterflies; one max; 16 independent exps. Pass 2: re-read the wave's
// 32KB enc window (L2-hot) and accumulate with independent FMAs.
// ---------------------------------------------------------------------------
__global__ __launch_bounds__(256) void attn_partial(
    const float* __restrict__ hprev, const float* __restrict__ enc,
    float* __restrict__ pm, float* __restrict__ pl, float* __restrict__ pacc)
{
  const int b = blockIdx.x >> 5;
  const int split = blockIdx.x & 31;
  const int t = threadIdx.x;
  const int w = t >> 6, lane = t & 63;

  const float* hb = hprev + b*HH + lane*8;
  const float4 h0 = *(const float4*)hb;
  const float4 h1 = *(const float4*)(hb + 4);
  const int s0 = split*64 + w*16;

  // ---- pass 1: 16 scores ----
  float d[16];
#pragma unroll 1
  for (int half = 0; half < 2; ++half) {
    float4 ea[8], eb[8];
#pragma unroll
    for (int i = 0; i < 8; ++i) {
      const float* ep = enc + ((size_t)(s0 + half*8 + i)*BB + b)*HH + lane*8;
      ea[i] = *(const float4*)ep; eb[i] = *(const float4*)(ep + 4);
    }
    float dd[8];
#pragma unroll
    for (int i = 0; i < 8; ++i) dd[i] = dot4(h0, ea[i]) + dot4(h1, eb[i]);
#pragma unroll
    for (int off = 32; off >= 1; off >>= 1) {
#pragma unroll
      for (int i = 0; i < 8; ++i) dd[i] += __shfl_xor(dd[i], off, 64);
    }
#pragma unroll
    for (int i = 0; i < 8; ++i) d[half*8 + i] = dd[i];
  }

  float m = d[0];
#pragma unroll
  for (int i = 1; i < 16; ++i) m = fmaxf(m, d[i]);
  float p[16];
  float lsum = 0.f;
#pragma unroll
  for (int i = 0; i < 16; ++i) { p[i] = __expf(d[i] - m); lsum += p[i]; }

  // ---- pass 2: weighted accumulate (enc window is L2-hot) ----
  float acc[8];
#pragma unroll
  for (int j = 0; j < 8; ++j) acc[j] = 0.f;
#pragma unroll 1
  for (int half = 0; half < 2; ++half) {
#pragma unroll
    for (int i = 0; i < 8; ++i) {
      const float* ep = enc + ((size_t)(s0 + half*8 + i)*BB + b)*HH + lane*8;
      const float4 ea = *(const float4*)ep;
      const float4 eb = *(const float4*)(ep + 4);
      const float pi = p[half*8 + i];
      acc[0] += pi*ea.x; acc[1] += pi*ea.y; acc[2] += pi*ea.z; acc[3] += pi*ea.w;
      acc[4] += pi*eb.x; acc[5] += pi*eb.y; acc[6] += pi*eb.z; acc[7] += pi*eb.w;
    }
  }

  // ---- combine 4 waves of the block ----
  __shared__ float sm4[4], sl4[4];
  __shared__ float sacc[4][HH];
  if (lane == 0) { sm4[w] = m; sl4[w] = lsum; }
  __syncthreads();
  const float M = fmaxf(fmaxf(sm4[0], sm4[1]), fmaxf(sm4[2], sm4[3]));
  const float ew = __expf(m - M);
#pragma unroll
  for (int j = 0; j < 8; ++j) sacc[w][lane*8 + j] = acc[j]*ew;
  __syncthreads();

  const int rec = blockIdx.x;
  for (int hh = t; hh < HH; hh += 256)
    pacc[(size_t)rec*HH + hh] = sacc[0][hh]+sacc[1][hh]+sacc[2][hh]+sacc[3][hh];
  if (t == 0) {
    float L = sl4[0]*__expf(sm4[0]-M) + sl4[1]*__expf(sm4[1]-M)
            + sl4[2]*__expf(sm4[2]-M) + sl4[3]*__expf(sm4[3]-M);
    pm[rec] = M; pl[rec] = L;
  }
}

// ---------------------------------------------------------------------------
// Kernel B: combine NSPLIT partials per b -> context -> featA (fragment order)
// ---------------------------------------------------------------------------
__global__ __launch_bounds__(256) void attn_reduce(
    const float* __restrict__ pm, const float* __restrict__ pl,
    const float* __restrict__ pacc, __hip_bfloat16* __restrict__ featA)
{
  const int b = blockIdx.x, t = threadIdx.x;
  __shared__ float smm[NSPLIT], sll[NSPLIT], sco[NSPLIT];
  if (t < NSPLIT) { smm[t] = pm[b*NSPLIT + t]; sll[t] = pl[b*NSPLIT + t]; }
  __syncthreads();
  float M = -INFINITY;
  for (int q = 0; q < NSPLIT; ++q) M = fmaxf(M, smm[q]);
  float L = 0.f;
  for (int q = 0; q < NSPLIT; ++q) L += sll[q]*__expf(smm[q]-M);
  const float inv = 1.f/L;
  if (t < NSPLIT) sco[t] = __expf(smm[t]-M)*inv;
  __syncthreads();
  const int hh0 = 2*t;
  float s0 = 0.f, s1 = 0.f;
  for (int q = 0; q < NSPLIT; ++q) {
    const float* pq = pacc + ((size_t)b*NSPLIT + q)*HH;
    s0 += pq[hh0]   * sco[q];
    s1 += pq[hh0+1] * sco[q];
  }
  const size_t a = fragAddr(b, HH + hh0);
  featA[a]   = (__hip_bfloat16)s0;
  featA[a+1] = (__hip_bfloat16)s1;
}

// ---------------------------------------------------------------------------
// Kernel C: GRU gates as MFMA GEMM (3 source segments). Weights read once.
// ---------------------------------------------------------------------------
__global__ __launch_bounds__(256) void gru_gemm(
    const int* __restrict__ last_out, const float* __restrict__ emb,
    const float* __restrict__ hprev, const __hip_bfloat16* __restrict__ featA,
    const float* __restrict__ W_ih, const float* __restrict__ W_hh,
    float* __restrict__ gates)
{
  const int gt  = blockIdx.x / 3;
  const int seg = blockIdx.x % 3;
  const int w = threadIdx.x >> 6, lane = threadIdx.x & 63;
  const int col = lane & 15, kg = lane >> 4;
  const int g = gt*64 + w*16 + col;

  const float* wrow = (seg == 2) ? (W_hh + (size_t)g*HH)
                                 : (W_ih + (size_t)g*KD + seg*HH);
  int lo_r[4];
#pragma unroll
  for (int mt = 0; mt < 4; ++mt) lo_r[mt] = last_out[mt*16 + col];

  f32x4 acc[4];
#pragma unroll
  for (int mt = 0; mt < 4; ++mt) acc[mt] = (f32x4){0.f,0.f,0.f,0.f};

  for (int k0 = 0; k0 < HH; k0 += 32) {
    const float* wp = wrow + k0 + kg*8;
    const bf16x8 bf = cvt8(*(const float4*)wp, *(const float4*)(wp+4));
#pragma unroll
    for (int mt = 0; mt < 4; ++mt) {
      const int bb = mt*16 + col;
      bf16x8 af;
      if (seg == 0) {
        const float* ap = emb + (size_t)lo_r[mt]*HH + k0 + kg*8;
        af = cvt8(*(const float4*)ap, *(const float4*)(ap+4));
      } else if (seg == 1) {
        af = *(const bf16x8*)(featA + fragAddr(bb, HH + k0 + kg*8));
      } else {
        const float* ap = hprev + (size_t)bb*HH + k0 + kg*8;
        af = cvt8(*(const float4*)ap, *(const float4*)(ap+4));
      }
      acc[mt] = __builtin_amdgcn_mfma_f32_16x16x32_bf16(af, bf, acc[mt], 0, 0, 0);
    }
  }

  float* gp = gates + (size_t)seg*BB*1536;
#pragma unroll
  for (int mt = 0; mt < 4; ++mt)
#pragma unroll
    for (int reg = 0; reg < 4; ++reg) {
      const int brow = mt*16 + kg*4 + reg;
      gp[(size_t)brow*1536 + g] = acc[mt][reg];
    }
}

// ---------------------------------------------------------------------------
// Kernel C2: GRU pointwise.
// ---------------------------------------------------------------------------
__global__ __launch_bounds__(512) void gru_pointwise(
    const float* __restrict__ gates, const float* __restrict__ hprev,
    const float* __restrict__ b_ih, const float* __restrict__ b_hh,
    float* __restrict__ hid_out, __hip_bfloat16* __restrict__ featA)
{
  const int b = blockIdx.x, j = threadIdx.x;
  const float* g0 = gates + (size_t)b*1536;
  const float* g1 = gates + (size_t)(BB + b)*1536;
  const float* g2 = gates + (size_t)(2*BB + b)*1536;

  const float i_r = g0[j]        + g1[j];
  const float i_z = g0[HH + j]   + g1[HH + j];
  const float i_n = g0[2*HH + j] + g1[2*HH + j];

  const float r = 1.f/(1.f + __expf(-(i_r + g2[j] + b_ih[j] + b_hh[j])));
  const float z = 1.f/(1.f + __expf(-(i_z + g2[HH+j] + b_ih[HH+j] + b_hh[HH+j])));
  const float n = tanhf(i_n + b_ih[2*HH+j] + r*(g2[2*HH+j] + b_hh[2*HH+j]));
  const float hp = hprev[b*HH + j];
  const float hn = (1.f - z)*n + z*hp;
  hid_out[b*HH + j] = hn;
  featA[fragAddr(b, j)] = (__hip_bfloat16)hn;
}

// ---------------------------------------------------------------------------
// Kernel D: logits GEMM (+bias) -> out, WITH fused per-tile lsm partials
// (verified in the R8 mega run). Register path, 1-deep rotating prefetch.
// ---------------------------------------------------------------------------
__global__ __launch_bounds__(256) void logits_gemm(
    const __hip_bfloat16* __restrict__ featA, const float* __restrict__ W_out,
    const float* __restrict__ b_out, float* __restrict__ out,
    float* __restrict__ pmE, float* __restrict__ plE)
{
  __shared__ float smem[64*65];
  const int tile = blockIdx.x;
  const int t = threadIdx.x;
  const int w = t >> 6, lane = t & 63;
  const int col = lane & 15, kg = lane >> 4;
  const int v = tile*64 + w*16 + col;
  const int vc = (v < VV) ? v : (VV - 1);

  const float* wp = W_out + (size_t)vc*KD + kg*8;
  const __hip_bfloat16* fp = featA + lane*8;

  f32x4 acc[4];
#pragma unroll
  for (int mt = 0; mt < 4; ++mt) acc[mt] = (f32x4){0.f,0.f,0.f,0.f};

  float4 wa = *(const float4*)(wp);
  float4 wb = *(const float4*)(wp + 4);
  bf16x8 a0 = *(const bf16x8*)(fp);
  bf16x8 a1 = *(const bf16x8*)(fp + 512);
  bf16x8 a2 = *(const bf16x8*)(fp + 1024);
  bf16x8 a3 = *(const bf16x8*)(fp + 1536);

  for (int k0 = 0; k0 < KD; k0 += 32) {
    const int kn = (k0 + 32 < KD) ? (k0 + 32) : 0;
    const float4 nwa = *(const float4*)(wp + kn);
    const float4 nwb = *(const float4*)(wp + kn + 4);
    const __hip_bfloat16* fn = fp + (kn >> 5)*2048;
    const bf16x8 n0 = *(const bf16x8*)(fn);
    const bf16x8 n1 = *(const bf16x8*)(fn + 512);
    const bf16x8 n2 = *(const bf16x8*)(fn + 1024);
    const bf16x8 n3 = *(const bf16x8*)(fn + 1536);

    const bf16x8 bf = cvt8(wa, wb);
    acc[0] = __builtin_amdgcn_mfma_f32_16x16x32_bf16(a0, bf, acc[0], 0, 0, 0);
    acc[1] = __builtin_amdgcn_mfma_f32_16x16x32_bf16(a1, bf, acc[1], 0, 0, 0);
    acc[2] = __builtin_amdgcn_mfma_f32_16x16x32_bf16(a2, bf, acc[2], 0, 0, 0);
    acc[3] = __builtin_amdgcn_mfma_f32_16x16x32_bf16(a3, bf, acc[3], 0, 0, 0);

    wa = nwa; wb = nwb; a0 = n0; a1 = n1; a2 = n2; a3 = n3;
  }

  const float bo = (v < VV) ? b_out[v] : 0.f;
#pragma unroll
  for (int mt = 0; mt < 4; ++mt)
#pragma unroll
    for (int reg = 0; reg < 4; ++reg) {
      const float val = acc[mt][reg] + bo;
      const int brow = mt*16 + kg*4 + reg;
      if (v < VV) out[(size_t)brow*VV + v] = val;
      smem[brow*65 + w*16 + col] = (v < VV) ? val : -INFINITY;
    }
  __syncthreads();
  if (t < 64) {
    float M = -INFINITY;
#pragma unroll 8
    for (int i = 0; i < 64; ++i) M = fmaxf(M, smem[t*65 + i]);
    float L = 0.f;
#pragma unroll 8
    for (int i = 0; i < 64; ++i) L += __expf(smem[t*65 + i] - M);
    pmE[t*1024 + tile] = M; plE[t*1024 + tile] = L;
  }
}

// ---------------------------------------------------------------------------
// Kernel E: per-row reduce of NTILE partials -> cvec[row]. One wave per row.
// ---------------------------------------------------------------------------
__global__ __launch_bounds__(256) void lsm_rowreduce(
    const float* __restrict__ pmE, const float* __restrict__ plE,
    float* __restrict__ cvec)
{
  const int t = threadIdx.x;
  const int w = t >> 6, lane = t & 63;
  const int row = blockIdx.x*4 + w;
  if (row >= BB) return;
  float M = -INFINITY, L = 0.f;
  for (int q = lane; q < NTILE; q += 64) {
    const float mq = pmE[row*1024 + q], lq = plE[row*1024 + q];
    const float mn = fmaxf(M, mq);
    L = L*__expf(M - mn) + lq*__expf(mq - mn);
    M = mn;
  }
#pragma unroll
  for (int off = 32; off >= 1; off >>= 1) {
    const float m2 = __shfl_xor(M, off, 64), l2 = __shfl_xor(L, off, 64);
    const float mn = fmaxf(M, m2);
    L = L*__expf(M - mn) + l2*__expf(m2 - mn);
    M = mn;
  }
  if (lane == 0) cvec[row] = M + logf(L);
}

// ---------------------------------------------------------------------------
// Kernel F: logits -= cvec[row] (verified in R8 mega phase G).
// ---------------------------------------------------------------------------
__global__ __launch_bounds__(256) void lsm_sub(
    float* __restrict__ out, const float* __restrict__ cvec)
{
  const unsigned total4 = (unsigned)(BB*(unsigned)VV/4u);
  const unsigned idx = blockIdx.x*256u + threadIdx.x;
  if (idx >= total4) return;
  const unsigned i = idx*4u;
  float4 v = *(float4*)(out + i);
  v.x -= cvec[i/VV];
  v.y -= cvec[(i+1)/VV];
  v.z -= cvec[(i+2)/VV];
  v.w -= cvec[(i+3)/VV];
  *(float4*)(out + i) = v;
}

// ---------------------------------------------------------------------------
extern "C" void kernel_launch(void* const* d_in, const int* in_sizes, int n_in,
                              void* d_out, int out_size, void* d_ws, size_t ws_size,
                              hipStream_t stream)
{
  const int*   last_output = (const int*)d_in[0];
  const float* last_hidden = (const float*)d_in[1];
  const float* enc         = (const float*)d_in[2];
  const float* emb         = (const float*)d_in[3];
  const float* W_ih        = (const float*)d_in[4];
  const float* b_ih        = (const float*)d_in[5];
  const float* W_hh        = (const float*)d_in[6];
  const float* b_hh        = (const float*)d_in[7];
  const float* W_out       = (const float*)d_in[8];
  const float* b_out       = (const float*)d_in[9];
  float* out = (float*)d_out;

  __hip_bfloat16* featA = (__hip_bfloat16*)d_ws;            // 128 KB
  float* gates = (float*)((char*)d_ws + 131072);            // 1.18 MB
  float* pm   = gates + (size_t)3*BB*1536;                  // 2048
  float* pl   = pm + BB*NSPLIT;                             // 2048
  float* pmE  = pl + BB*NSPLIT;                             // 64*1024
  float* plE  = pmE + BB*1024;                              // 64*1024
  float* cvec = plE + BB*1024;                              // 64
  float* pacc = out;   // 4 MB parked in dead logits region
  float* hid_out = out + (size_t)BB*VV;

  attn_partial <<<dim3(BB*NSPLIT), dim3(256), 0, stream>>>(last_hidden, enc, pm, pl, pacc);
  attn_reduce  <<<dim3(BB),        dim3(256), 0, stream>>>(pm, pl, pacc, featA);
  gru_gemm     <<<dim3(24*3),      dim3(256), 0, stream>>>(last_output, emb, last_hidden,
                                                           featA, W_ih, W_hh, gates);
  gru_pointwise<<<dim3(BB),        dim3(512), 0, stream>>>(gates, last_hidden, b_ih, b_hh,
                                                           hid_out, featA);
  logits_gemm  <<<dim3(NTILE),     dim3(256), 0, stream>>>(featA, W_out, b_out, out, pmE, plE);
  lsm_rowreduce<<<dim3(16),        dim3(256), 0, stream>>>(pmE, plE, cvec);
  lsm_sub      <<<dim3((int)(((size_t)BB*VV/4 + 255)/256)), dim3(256), 0, stream>>>(out, cvec);
}

// Round 10
// 199.145 us; speedup vs baseline: 1.9121x; 1.1509x over previous
//
#include <hip/hip_runtime.h>
#include <hip/hip_bf16.h>
#include <math.h>

#define BB 64
#define SS 2048
#define HH 512
#define VV 50257
#define KD 1024    // I + H
#define NSPLIT 32  // attn s-chunks per batch row
#define NTILE 786  // ceil(VV/64)

typedef float f32x4 __attribute__((ext_vector_type(4)));
typedef __bf16 bf16x8 __attribute__((ext_vector_type(8)));

__device__ __forceinline__ float dot4(float4 a, float4 b) {
  return a.x*b.x + a.y*b.y + a.z*b.z + a.w*b.w;
}

__device__ __forceinline__ bf16x8 cvt8(float4 a, float4 b) {
  bf16x8 r;
  r[0]=(__bf16)a.x; r[1]=(__bf16)a.y; r[2]=(__bf16)a.z; r[3]=(__bf16)a.w;
  r[4]=(__bf16)b.x; r[5]=(__bf16)b.y; r[6]=(__bf16)b.z; r[7]=(__bf16)b.w;
  return r;
}

// featA fragment-linear layout: element (b, k) lives at
//   (k>>5)*2048 + (b>>4)*512 + ((k>>3)&3)*128 + (b&15)*8 + (k&7)
__device__ __forceinline__ size_t fragAddr(int b, int k) {
  return (size_t)(k >> 5)*2048 + (size_t)(b >> 4)*512
       + (size_t)((k >> 3) & 3)*128 + (size_t)(b & 15)*8 + (size_t)(k & 7);
}

// ---------------------------------------------------------------------------
// Kernel A: attention partials. SINGLE enc read (e held in registers per
// half of 8 s-rows); online rescale only between the two halves.
// Serial chain per rec = 2 segments; within a segment all ops independent.
// ---------------------------------------------------------------------------
__global__ __launch_bounds__(256) void attn_partial(
    const float* __restrict__ hprev, const float* __restrict__ enc,
    float* __restrict__ pm, float* __restrict__ pl, float* __restrict__ pacc)
{
  const int b = blockIdx.x >> 5;
  const int split = blockIdx.x & 31;
  const int t = threadIdx.x;
  const int w = t >> 6, lane = t & 63;

  const float* hb = hprev + b*HH + lane*8;
  const float4 h0 = *(const float4*)hb;
  const float4 h1 = *(const float4*)(hb + 4);
  const int s0 = split*64 + w*16;

  float m = -INFINITY, lsum = 0.f;
  float acc[8];
#pragma unroll
  for (int j = 0; j < 8; ++j) acc[j] = 0.f;

#pragma unroll 1
  for (int half = 0; half < 2; ++half) {
    float4 ea[8], eb[8];
#pragma unroll
    for (int i = 0; i < 8; ++i) {
      const float* ep = enc + ((size_t)(s0 + half*8 + i)*BB + b)*HH + lane*8;
      ea[i] = *(const float4*)ep; eb[i] = *(const float4*)(ep + 4);
    }
    float dd[8];
#pragma unroll
    for (int i = 0; i < 8; ++i) dd[i] = dot4(h0, ea[i]) + dot4(h1, eb[i]);
#pragma unroll
    for (int off = 32; off >= 1; off >>= 1) {
#pragma unroll
      for (int i = 0; i < 8; ++i) dd[i] += __shfl_xor(dd[i], off, 64);
    }
    float hm = dd[0];
#pragma unroll
    for (int i = 1; i < 8; ++i) hm = fmaxf(hm, dd[i]);
    const float mn = fmaxf(m, hm);
    const float sc = __expf(m - mn);   // half 0: exp(-inf)=0
    float p[8], psum = 0.f;
#pragma unroll
    for (int i = 0; i < 8; ++i) { p[i] = __expf(dd[i] - mn); psum += p[i]; }
    lsum = lsum*sc + psum;
#pragma unroll
    for (int j = 0; j < 8; ++j) acc[j] *= sc;
#pragma unroll
    for (int i = 0; i < 8; ++i) {
      acc[0] += p[i]*ea[i].x; acc[1] += p[i]*ea[i].y;
      acc[2] += p[i]*ea[i].z; acc[3] += p[i]*ea[i].w;
      acc[4] += p[i]*eb[i].x; acc[5] += p[i]*eb[i].y;
      acc[6] += p[i]*eb[i].z; acc[7] += p[i]*eb[i].w;
    }
    m = mn;
  }

  // ---- combine 4 waves of the block ----
  __shared__ float sm4[4], sl4[4];
  __shared__ float sacc[4][HH];
  if (lane == 0) { sm4[w] = m; sl4[w] = lsum; }
  __syncthreads();
  const float M = fmaxf(fmaxf(sm4[0], sm4[1]), fmaxf(sm4[2], sm4[3]));
  const float ew = __expf(m - M);
#pragma unroll
  for (int j = 0; j < 8; ++j) sacc[w][lane*8 + j] = acc[j]*ew;
  __syncthreads();

  const int rec = blockIdx.x;
  for (int hh = t; hh < HH; hh += 256)
    pacc[(size_t)rec*HH + hh] = sacc[0][hh]+sacc[1][hh]+sacc[2][hh]+sacc[3][hh];
  if (t == 0) {
    float L = sl4[0]*__expf(sm4[0]-M) + sl4[1]*__expf(sm4[1]-M)
            + sl4[2]*__expf(sm4[2]-M) + sl4[3]*__expf(sm4[3]-M);
    pm[rec] = M; pl[rec] = L;
  }
}

// ---------------------------------------------------------------------------
// Kernel B: combine NSPLIT partials per b -> context -> featA (fragment order)
// ---------------------------------------------------------------------------
__global__ __launch_bounds__(256) void attn_reduce(
    const float* __restrict__ pm, const float* __restrict__ pl,
    const float* __restrict__ pacc, __hip_bfloat16* __restrict__ featA)
{
  const int b = blockIdx.x, t = threadIdx.x;
  __shared__ float smm[NSPLIT], sll[NSPLIT], sco[NSPLIT];
  if (t < NSPLIT) { smm[t] = pm[b*NSPLIT + t]; sll[t] = pl[b*NSPLIT + t]; }
  __syncthreads();
  float M = -INFINITY;
  for (int q = 0; q < NSPLIT; ++q) M = fmaxf(M, smm[q]);
  float L = 0.f;
  for (int q = 0; q < NSPLIT; ++q) L += sll[q]*__expf(smm[q]-M);
  const float inv = 1.f/L;
  if (t < NSPLIT) sco[t] = __expf(smm[t]-M)*inv;
  __syncthreads();
  const int hh0 = 2*t;
  float s0 = 0.f, s1 = 0.f;
  for (int q = 0; q < NSPLIT; ++q) {
    const float* pq = pacc + ((size_t)b*NSPLIT + q)*HH;
    s0 += pq[hh0]   * sco[q];
    s1 += pq[hh0+1] * sco[q];
  }
  const size_t a = fragAddr(b, HH + hh0);
  featA[a]   = (__hip_bfloat16)s0;
  featA[a+1] = (__hip_bfloat16)s1;
}

// ---------------------------------------------------------------------------
// Kernel C: GRU gates as MFMA GEMM (3 source segments). Weights read once.
// ---------------------------------------------------------------------------
__global__ __launch_bounds__(256) void gru_gemm(
    const int* __restrict__ last_out, const float* __restrict__ emb,
    const float* __restrict__ hprev, const __hip_bfloat16* __restrict__ featA,
    const float* __restrict__ W_ih, const float* __restrict__ W_hh,
    float* __restrict__ gates)
{
  const int gt  = blockIdx.x / 3;
  const int seg = blockIdx.x % 3;
  const int w = threadIdx.x >> 6, lane = threadIdx.x & 63;
  const int col = lane & 15, kg = lane >> 4;
  const int g = gt*64 + w*16 + col;

  const float* wrow = (seg == 2) ? (W_hh + (size_t)g*HH)
                                 : (W_ih + (size_t)g*KD + seg*HH);
  int lo_r[4];
#pragma unroll
  for (int mt = 0; mt < 4; ++mt) lo_r[mt] = last_out[mt*16 + col];

  f32x4 acc[4];
#pragma unroll
  for (int mt = 0; mt < 4; ++mt) acc[mt] = (f32x4){0.f,0.f,0.f,0.f};

  for (int k0 = 0; k0 < HH; k0 += 32) {
    const float* wp = wrow + k0 + kg*8;
    const bf16x8 bf = cvt8(*(const float4*)wp, *(const float4*)(wp+4));
#pragma unroll
    for (int mt = 0; mt < 4; ++mt) {
      const int bb = mt*16 + col;
      bf16x8 af;
      if (seg == 0) {
        const float* ap = emb + (size_t)lo_r[mt]*HH + k0 + kg*8;
        af = cvt8(*(const float4*)ap, *(const float4*)(ap+4));
      } else if (seg == 1) {
        af = *(const bf16x8*)(featA + fragAddr(bb, HH + k0 + kg*8));
      } else {
        const float* ap = hprev + (size_t)bb*HH + k0 + kg*8;
        af = cvt8(*(const float4*)ap, *(const float4*)(ap+4));
      }
      acc[mt] = __builtin_amdgcn_mfma_f32_16x16x32_bf16(af, bf, acc[mt], 0, 0, 0);
    }
  }

  float* gp = gates + (size_t)seg*BB*1536;
#pragma unroll
  for (int mt = 0; mt < 4; ++mt)
#pragma unroll
    for (int reg = 0; reg < 4; ++reg) {
      const int brow = mt*16 + kg*4 + reg;
      gp[(size_t)brow*1536 + g] = acc[mt][reg];
    }
}

// ---------------------------------------------------------------------------
// Kernel C2: GRU pointwise.
// ---------------------------------------------------------------------------
__global__ __launch_bounds__(512) void gru_pointwise(
    const float* __restrict__ gates, const float* __restrict__ hprev,
    const float* __restrict__ b_ih, const float* __restrict__ b_hh,
    float* __restrict__ hid_out, __hip_bfloat16* __restrict__ featA)
{
  const int b = blockIdx.x, j = threadIdx.x;
  const float* g0 = gates + (size_t)b*1536;
  const float* g1 = gates + (size_t)(BB + b)*1536;
  const float* g2 = gates + (size_t)(2*BB + b)*1536;

  const float i_r = g0[j]        + g1[j];
  const float i_z = g0[HH + j]   + g1[HH + j];
  const float i_n = g0[2*HH + j] + g1[2*HH + j];

  const float r = 1.f/(1.f + __expf(-(i_r + g2[j] + b_ih[j] + b_hh[j])));
  const float z = 1.f/(1.f + __expf(-(i_z + g2[HH+j] + b_ih[HH+j] + b_hh[HH+j])));
  const float n = tanhf(i_n + b_ih[2*HH+j] + r*(g2[2*HH+j] + b_hh[2*HH+j]));
  const float hp = hprev[b*HH + j];
  const float hn = (1.f - z)*n + z*hp;
  hid_out[b*HH + j] = hn;
  featA[fragAddr(b, j)] = (__hip_bfloat16)hn;
}

// ---------------------------------------------------------------------------
// Kernel D: logits GEMM (+bias) -> out, fused per-tile lsm partials.
// ---------------------------------------------------------------------------
__global__ __launch_bounds__(256) void logits_gemm(
    const __hip_bfloat16* __restrict__ featA, const float* __restrict__ W_out,
    const float* __restrict__ b_out, float* __restrict__ out,
    float* __restrict__ pmE, float* __restrict__ plE)
{
  __shared__ float smem[64*65];
  const int tile = blockIdx.x;
  const int t = threadIdx.x;
  const int w = t >> 6, lane = t & 63;
  const int col = lane & 15, kg = lane >> 4;
  const int v = tile*64 + w*16 + col;
  const int vc = (v < VV) ? v : (VV - 1);

  const float* wp = W_out + (size_t)vc*KD + kg*8;
  const __hip_bfloat16* fp = featA + lane*8;

  f32x4 acc[4];
#pragma unroll
  for (int mt = 0; mt < 4; ++mt) acc[mt] = (f32x4){0.f,0.f,0.f,0.f};

  float4 wa = *(const float4*)(wp);
  float4 wb = *(const float4*)(wp + 4);
  bf16x8 a0 = *(const bf16x8*)(fp);
  bf16x8 a1 = *(const bf16x8*)(fp + 512);
  bf16x8 a2 = *(const bf16x8*)(fp + 1024);
  bf16x8 a3 = *(const bf16x8*)(fp + 1536);

  for (int k0 = 0; k0 < KD; k0 += 32) {
    const int kn = (k0 + 32 < KD) ? (k0 + 32) : 0;
    const float4 nwa = *(const float4*)(wp + kn);
    const float4 nwb = *(const float4*)(wp + kn + 4);
    const __hip_bfloat16* fn = fp + (kn >> 5)*2048;
    const bf16x8 n0 = *(const bf16x8*)(fn);
    const bf16x8 n1 = *(const bf16x8*)(fn + 512);
    const bf16x8 n2 = *(const bf16x8*)(fn + 1024);
    const bf16x8 n3 = *(const bf16x8*)(fn + 1536);

    const bf16x8 bf = cvt8(wa, wb);
    acc[0] = __builtin_amdgcn_mfma_f32_16x16x32_bf16(a0, bf, acc[0], 0, 0, 0);
    acc[1] = __builtin_amdgcn_mfma_f32_16x16x32_bf16(a1, bf, acc[1], 0, 0, 0);
    acc[2] = __builtin_amdgcn_mfma_f32_16x16x32_bf16(a2, bf, acc[2], 0, 0, 0);
    acc[3] = __builtin_amdgcn_mfma_f32_16x16x32_bf16(a3, bf, acc[3], 0, 0, 0);

    wa = nwa; wb = nwb; a0 = n0; a1 = n1; a2 = n2; a3 = n3;
  }

  const float bo = (v < VV) ? b_out[v] : 0.f;
#pragma unroll
  for (int mt = 0; mt < 4; ++mt)
#pragma unroll
    for (int reg = 0; reg < 4; ++reg) {
      const float val = acc[mt][reg] + bo;
      const int brow = mt*16 + kg*4 + reg;
      if (v < VV) out[(size_t)brow*VV + v] = val;
      smem[brow*65 + w*16 + col] = (v < VV) ? val : -INFINITY;
    }
  __syncthreads();
  if (t < 64) {
    float M = -INFINITY;
#pragma unroll 8
    for (int i = 0; i < 64; ++i) M = fmaxf(M, smem[t*65 + i]);
    float L = 0.f;
#pragma unroll 8
    for (int i = 0; i < 64; ++i) L += __expf(smem[t*65 + i] - M);
    pmE[t*1024 + tile] = M; plE[t*1024 + tile] = L;
  }
}

// ---------------------------------------------------------------------------
// Kernel E: per-row reduce of NTILE partials -> cvec[row]. One wave per row.
// ---------------------------------------------------------------------------
__global__ __launch_bounds__(256) void lsm_rowreduce(
    const float* __restrict__ pmE, const float* __restrict__ plE,
    float* __restrict__ cvec)
{
  const int t = threadIdx.x;
  const int w = t >> 6, lane = t & 63;
  const int row = blockIdx.x*4 + w;
  if (row >= BB) return;
  float M = -INFINITY, L = 0.f;
  for (int q = lane; q < NTILE; q += 64) {
    const float mq = pmE[row*1024 + q], lq = plE[row*1024 + q];
    const float mn = fmaxf(M, mq);
    L = L*__expf(M - mn) + lq*__expf(mq - mn);
    M = mn;
  }
#pragma unroll
  for (int off = 32; off >= 1; off >>= 1) {
    const float m2 = __shfl_xor(M, off, 64), l2 = __shfl_xor(L, off, 64);
    const float mn = fmaxf(M, m2);
    L = L*__expf(M - mn) + l2*__expf(m2 - mn);
    M = mn;
  }
  if (lane == 0) cvec[row] = M + logf(L);
}

// ---------------------------------------------------------------------------
// Kernel F: logits -= cvec[row].
// ---------------------------------------------------------------------------
__global__ __launch_bounds__(256) void lsm_sub(
    float* __restrict__ out, const float* __restrict__ cvec)
{
  const unsigned total4 = (unsigned)(BB*(unsigned)VV/4u);
  const unsigned idx = blockIdx.x*256u + threadIdx.x;
  if (idx >= total4) return;
  const unsigned i = idx*4u;
  float4 v = *(float4*)(out + i);
  v.x -= cvec[i/VV];
  v.y -= cvec[(i+1)/VV];
  v.z -= cvec[(i+2)/VV];
  v.w -= cvec[(i+3)/VV];
  *(float4*)(out + i) = v;
}

// ---------------------------------------------------------------------------
extern "C" void kernel_launch(void* const* d_in, const int* in_sizes, int n_in,
                              void* d_out, int out_size, void* d_ws, size_t ws_size,
                              hipStream_t stream)
{
  const int*   last_output = (const int*)d_in[0];
  const float* last_hidden = (const float*)d_in[1];
  const float* enc         = (const float*)d_in[2];
  const float* emb         = (const float*)d_in[3];
  const float* W_ih        = (const float*)d_in[4];
  const float* b_ih        = (const float*)d_in[5];
  const float* W_hh        = (const float*)d_in[6];
  const float* b_hh        = (const float*)d_in[7];
  const float* W_out       = (const float*)d_in[8];
  const float* b_out       = (const float*)d_in[9];
  float* out = (float*)d_out;

  __hip_bfloat16* featA = (__hip_bfloat16*)d_ws;            // 128 KB
  float* gates = (float*)((char*)d_ws + 131072);            // 1.18 MB
  float* pm   = gates + (size_t)3*BB*1536;                  // 2048
  float* pl   = pm + BB*NSPLIT;                             // 2048
  float* pmE  = pl + BB*NSPLIT;                             // 64*1024
  float* plE  = pmE + BB*1024;                              // 64*1024
  float* cvec = plE + BB*1024;                              // 64
  float* pacc = out;   // 4 MB parked in dead logits region
  float* hid_out = out + (size_t)BB*VV;

  attn_partial <<<dim3(BB*NSPLIT), dim3(256), 0, stream>>>(last_hidden, enc, pm, pl, pacc);
  attn_reduce  <<<dim3(BB),        dim3(256), 0, stream>>>(pm, pl, pacc, featA);
  gru_gemm     <<<dim3(24*3),      dim3(256), 0, stream>>>(last_output, emb, last_hidden,
                                                           featA, W_ih, W_hh, gates);
  gru_pointwise<<<dim3(BB),        dim3(512), 0, stream>>>(gates, last_hidden, b_ih, b_hh,
                                                           hid_out, featA);
  logits_gemm  <<<dim3(NTILE),     dim3(256), 0, stream>>>(featA, W_out, b_out, out, pmE, plE);
  lsm_rowreduce<<<dim3(16),        dim3(256), 0, stream>>>(pmE, plE, cvec);
  lsm_sub      <<<dim3((int)(((size_t)BB*VV/4 + 255)/256)), dim3(256), 0, stream>>>(out, cvec);
}

// Round 12
// 165.262 us; speedup vs baseline: 2.3041x; 1.2050x over previous
//
#include <hip/hip_runtime.h>
#include <hip/hip_bf16.h>
#include <math.h>

#define BB 64
#define SS 2048
#define HH 512
#define VV 50257
#define KD 1024    // I + H
#define NSPLIT 32  // attn s-chunks per batch row
#define NTILE 786  // ceil(VV/64)

typedef float f32x4 __attribute__((ext_vector_type(4)));
typedef __bf16 bf16x8 __attribute__((ext_vector_type(8)));

__device__ __forceinline__ float dot4(float4 a, float4 b) {
  return a.x*b.x + a.y*b.y + a.z*b.z + a.w*b.w;
}

__device__ __forceinline__ bf16x8 cvt8(float4 a, float4 b) {
  bf16x8 r;
  r[0]=(__bf16)a.x; r[1]=(__bf16)a.y; r[2]=(__bf16)a.z; r[3]=(__bf16)a.w;
  r[4]=(__bf16)b.x; r[5]=(__bf16)b.y; r[6]=(__bf16)b.z; r[7]=(__bf16)b.w;
  return r;
}

// featA fragment-linear layout: element (b, k) lives at
//   (k>>5)*2048 + (b>>4)*512 + ((k>>3)&3)*128 + (b&15)*8 + (k&7)
__device__ __forceinline__ size_t fragAddr(int b, int k) {
  return (size_t)(k >> 5)*2048 + (size_t)(b >> 4)*512
       + (size_t)((k >> 3) & 3)*128 + (size_t)(b & 15)*8 + (size_t)(k & 7);
}

// ---------------------------------------------------------------------------
// Kernel A: attention partials (R10 version — near BW-bound, keep).
// ---------------------------------------------------------------------------
__global__ __launch_bounds__(256) void attn_partial(
    const float* __restrict__ hprev, const float* __restrict__ enc,
    float* __restrict__ pm, float* __restrict__ pl, float* __restrict__ pacc)
{
  const int b = blockIdx.x >> 5;
  const int split = blockIdx.x & 31;
  const int t = threadIdx.x;
  const int w = t >> 6, lane = t & 63;

  const float* hb = hprev + b*HH + lane*8;
  const float4 h0 = *(const float4*)hb;
  const float4 h1 = *(const float4*)(hb + 4);
  const int s0 = split*64 + w*16;

  float m = -INFINITY, lsum = 0.f;
  float acc[8];
#pragma unroll
  for (int j = 0; j < 8; ++j) acc[j] = 0.f;

#pragma unroll 1
  for (int half = 0; half < 2; ++half) {
    float4 ea[8], eb[8];
#pragma unroll
    for (int i = 0; i < 8; ++i) {
      const float* ep = enc + ((size_t)(s0 + half*8 + i)*BB + b)*HH + lane*8;
      ea[i] = *(const float4*)ep; eb[i] = *(const float4*)(ep + 4);
    }
    float dd[8];
#pragma unroll
    for (int i = 0; i < 8; ++i) dd[i] = dot4(h0, ea[i]) + dot4(h1, eb[i]);
#pragma unroll
    for (int off = 32; off >= 1; off >>= 1) {
#pragma unroll
      for (int i = 0; i < 8; ++i) dd[i] += __shfl_xor(dd[i], off, 64);
    }
    float hm = dd[0];
#pragma unroll
    for (int i = 1; i < 8; ++i) hm = fmaxf(hm, dd[i]);
    const float mn = fmaxf(m, hm);
    const float sc = __expf(m - mn);
    float p[8], psum = 0.f;
#pragma unroll
    for (int i = 0; i < 8; ++i) { p[i] = __expf(dd[i] - mn); psum += p[i]; }
    lsum = lsum*sc + psum;
#pragma unroll
    for (int j = 0; j < 8; ++j) acc[j] *= sc;
#pragma unroll
    for (int i = 0; i < 8; ++i) {
      acc[0] += p[i]*ea[i].x; acc[1] += p[i]*ea[i].y;
      acc[2] += p[i]*ea[i].z; acc[3] += p[i]*ea[i].w;
      acc[4] += p[i]*eb[i].x; acc[5] += p[i]*eb[i].y;
      acc[6] += p[i]*eb[i].z; acc[7] += p[i]*eb[i].w;
    }
    m = mn;
  }

  __shared__ float sm4[4], sl4[4];
  __shared__ float sacc[4][HH];
  if (lane == 0) { sm4[w] = m; sl4[w] = lsum; }
  __syncthreads();
  const float M = fmaxf(fmaxf(sm4[0], sm4[1]), fmaxf(sm4[2], sm4[3]));
  const float ew = __expf(m - M);
#pragma unroll
  for (int j = 0; j < 8; ++j) sacc[w][lane*8 + j] = acc[j]*ew;
  __syncthreads();

  const int rec = blockIdx.x;
  for (int hh = t; hh < HH; hh += 256)
    pacc[(size_t)rec*HH + hh] = sacc[0][hh]+sacc[1][hh]+sacc[2][hh]+sacc[3][hh];
  if (t == 0) {
    float L = sl4[0]*__expf(sm4[0]-M) + sl4[1]*__expf(sm4[1]-M)
            + sl4[2]*__expf(sm4[2]-M) + sl4[3]*__expf(sm4[3]-M);
    pm[rec] = M; pl[rec] = L;
  }
}

// ---------------------------------------------------------------------------
// Kernel B: combine NSPLIT partials per b -> context -> featA (fragment order)
// ---------------------------------------------------------------------------
__global__ __launch_bounds__(256) void attn_reduce(
    const float* __restrict__ pm, const float* __restrict__ pl,
    const float* __restrict__ pacc, __hip_bfloat16* __restrict__ featA)
{
  const int b = blockIdx.x, t = threadIdx.x;
  __shared__ float smm[NSPLIT], sll[NSPLIT], sco[NSPLIT];
  if (t < NSPLIT) { smm[t] = pm[b*NSPLIT + t]; sll[t] = pl[b*NSPLIT + t]; }
  __syncthreads();
  float M = -INFINITY;
  for (int q = 0; q < NSPLIT; ++q) M = fmaxf(M, smm[q]);
  float L = 0.f;
  for (int q = 0; q < NSPLIT; ++q) L += sll[q]*__expf(smm[q]-M);
  const float inv = 1.f/L;
  if (t < NSPLIT) sco[t] = __expf(smm[t]-M)*inv;
  __syncthreads();
  const int hh0 = 2*t;
  float s0 = 0.f, s1 = 0.f;
  for (int q = 0; q < NSPLIT; ++q) {
    const float* pq = pacc + ((size_t)b*NSPLIT + q)*HH;
    s0 += pq[hh0]   * sco[q];
    s1 += pq[hh0+1] * sco[q];
  }
  const size_t a = fragAddr(b, HH + hh0);
  featA[a]   = (__hip_bfloat16)s0;
  featA[a+1] = (__hip_bfloat16)s1;
}

// ---------------------------------------------------------------------------
// Kernel C: GRU gates GEMM, K-split x4 -> 288 blocks.
// ---------------------------------------------------------------------------
__global__ __launch_bounds__(256) void gru_gemm(
    const int* __restrict__ last_out, const float* __restrict__ emb,
    const float* __restrict__ hprev, const __hip_bfloat16* __restrict__ featA,
    const float* __restrict__ W_ih, const float* __restrict__ W_hh,
    float* __restrict__ gates)
{
  const int u = blockIdx.x;
  const int gt = u / 12;
  const int rem = u % 12;
  const int seg = rem >> 2, ks = rem & 3;
  const int w = threadIdx.x >> 6, lane = threadIdx.x & 63;
  const int col = lane & 15, kg = lane >> 4;
  const int g = gt*64 + w*16 + col;

  const float* wrow = (seg == 2) ? (W_hh + (size_t)g*HH)
                                 : (W_ih + (size_t)g*KD + seg*HH);
  int lo_r[4];
#pragma unroll
  for (int mt = 0; mt < 4; ++mt) lo_r[mt] = last_out[mt*16 + col];

  f32x4 acc[4];
#pragma unroll
  for (int mt = 0; mt < 4; ++mt) acc[mt] = (f32x4){0.f,0.f,0.f,0.f};

  const int kbeg = ks*128, kend = kbeg + 128;
  for (int k0 = kbeg; k0 < kend; k0 += 32) {
    const float* wp = wrow + k0 + kg*8;
    const bf16x8 bf = cvt8(*(const float4*)wp, *(const float4*)(wp+4));
#pragma unroll
    for (int mt = 0; mt < 4; ++mt) {
      const int bb = mt*16 + col;
      bf16x8 af;
      if (seg == 0) {
        const float* ap = emb + (size_t)lo_r[mt]*HH + k0 + kg*8;
        af = cvt8(*(const float4*)ap, *(const float4*)(ap+4));
      } else if (seg == 1) {
        af = *(const bf16x8*)(featA + fragAddr(bb, HH + k0 + kg*8));
      } else {
        const float* ap = hprev + (size_t)bb*HH + k0 + kg*8;
        af = cvt8(*(const float4*)ap, *(const float4*)(ap+4));
      }
      acc[mt] = __builtin_amdgcn_mfma_f32_16x16x32_bf16(af, bf, acc[mt], 0, 0, 0);
    }
  }

  float* gp = gates + (size_t)rem*BB*1536;
#pragma unroll
  for (int mt = 0; mt < 4; ++mt)
#pragma unroll
    for (int reg = 0; reg < 4; ++reg) {
      const int brow = mt*16 + kg*4 + reg;
      gp[(size_t)brow*1536 + g] = acc[mt][reg];
    }
}

// ---------------------------------------------------------------------------
// Kernel C2: GRU pointwise, sums 12 partials.
// ---------------------------------------------------------------------------
__global__ __launch_bounds__(512) void gru_pointwise(
    const float* __restrict__ gates, const float* __restrict__ hprev,
    const float* __restrict__ b_ih, const float* __restrict__ b_hh,
    float* __restrict__ hid_out, __hip_bfloat16* __restrict__ featA)
{
  const int b = blockIdx.x, j = threadIdx.x;

  float i_r = 0.f, i_z = 0.f, i_n = 0.f;
#pragma unroll
  for (int p = 0; p < 8; ++p) {
    const float* gp = gates + ((size_t)p*BB + b)*1536;
    i_r += gp[j]; i_z += gp[HH + j]; i_n += gp[2*HH + j];
  }
  float h_r = 0.f, h_z = 0.f, h_n = 0.f;
#pragma unroll
  for (int p = 8; p < 12; ++p) {
    const float* gp = gates + ((size_t)p*BB + b)*1536;
    h_r += gp[j]; h_z += gp[HH + j]; h_n += gp[2*HH + j];
  }

  const float r = 1.f/(1.f + __expf(-(i_r + h_r + b_ih[j] + b_hh[j])));
  const float z = 1.f/(1.f + __expf(-(i_z + h_z + b_ih[HH+j] + b_hh[HH+j])));
  const float n = tanhf(i_n + b_ih[2*HH+j] + r*(h_n + b_hh[2*HH+j]));
  const float hp = hprev[b*HH + j];
  const float hn = (1.f - z)*n + z*hp;
  hid_out[b*HH + j] = hn;
  featA[fragAddr(b, j)] = (__hip_bfloat16)hn;
}

// ---------------------------------------------------------------------------
// Kernel D: logits GEMM (+bias) -> out, fused lsm partials.
// 3-slot rotating register pipeline (2 k-steps in flight), fully unrolled.
// Two-stage lsm partial with EMPTY-QUADRANT GUARDS (R11 NaN fix).
// ---------------------------------------------------------------------------
__global__ __launch_bounds__(256) void logits_gemm(
    const __hip_bfloat16* __restrict__ featA, const float* __restrict__ W_out,
    const float* __restrict__ b_out, float* __restrict__ out,
    float* __restrict__ pmE, float* __restrict__ plE)
{
  __shared__ float vals[64*65];
  __shared__ float pMq[4*64], pLq[4*64];
  const int tile = blockIdx.x;
  const int t = threadIdx.x;
  const int w = t >> 6, lane = t & 63;
  const int col = lane & 15, kg = lane >> 4;
  const int v = tile*64 + w*16 + col;
  const int vc = (v < VV) ? v : (VV - 1);

  const float* wp = W_out + (size_t)vc*KD + kg*8;
  const __hip_bfloat16* fp = featA + lane*8;

  f32x4 acc[4];
#pragma unroll
  for (int mt = 0; mt < 4; ++mt) acc[mt] = (f32x4){0.f,0.f,0.f,0.f};

  float4 WA[3], WB[3];
  bf16x8 AF[3][4];

#pragma unroll
  for (int s = 0; s < 2; ++s) {
    WA[s] = *(const float4*)(wp + s*32);
    WB[s] = *(const float4*)(wp + s*32 + 4);
    const __hip_bfloat16* f = fp + s*2048;
    AF[s][0] = *(const bf16x8*)(f);
    AF[s][1] = *(const bf16x8*)(f + 512);
    AF[s][2] = *(const bf16x8*)(f + 1024);
    AF[s][3] = *(const bf16x8*)(f + 1536);
  }

#pragma unroll
  for (int kc = 0; kc < 32; ++kc) {
    if (kc + 2 < 32) {
      const int s = (kc + 2) % 3;
      WA[s] = *(const float4*)(wp + (kc+2)*32);
      WB[s] = *(const float4*)(wp + (kc+2)*32 + 4);
      const __hip_bfloat16* f = fp + (kc+2)*2048;
      AF[s][0] = *(const bf16x8*)(f);
      AF[s][1] = *(const bf16x8*)(f + 512);
      AF[s][2] = *(const bf16x8*)(f + 1024);
      AF[s][3] = *(const bf16x8*)(f + 1536);
    }
    const int c = kc % 3;
    const bf16x8 bf = cvt8(WA[c], WB[c]);
    acc[0] = __builtin_amdgcn_mfma_f32_16x16x32_bf16(AF[c][0], bf, acc[0], 0, 0, 0);
    acc[1] = __builtin_amdgcn_mfma_f32_16x16x32_bf16(AF[c][1], bf, acc[1], 0, 0, 0);
    acc[2] = __builtin_amdgcn_mfma_f32_16x16x32_bf16(AF[c][2], bf, acc[2], 0, 0, 0);
    acc[3] = __builtin_amdgcn_mfma_f32_16x16x32_bf16(AF[c][3], bf, acc[3], 0, 0, 0);
  }

  const float bo = (v < VV) ? b_out[v] : 0.f;
#pragma unroll
  for (int mt = 0; mt < 4; ++mt)
#pragma unroll
    for (int reg = 0; reg < 4; ++reg) {
      const float val = acc[mt][reg] + bo;
      const int brow = mt*16 + kg*4 + reg;
      if (v < VV) out[(size_t)brow*VV + v] = val;
      vals[brow*65 + w*16 + col] = (v < VV) ? val : -INFINITY;
    }
  __syncthreads();

  // two-stage lsm partial with empty-quadrant guards
  {
    const int row = t & 63, q = t >> 6;
    const float* vr = vals + row*65 + q*16;
    float M = -INFINITY;
#pragma unroll
    for (int i = 0; i < 16; ++i) M = fmaxf(M, vr[i]);
    float L = 0.f;
    if (M > -INFINITY) {
#pragma unroll
      for (int i = 0; i < 16; ++i) L += __expf(vr[i] - M);
    }
    pMq[q*64 + row] = M; pLq[q*64 + row] = L;
  }
  __syncthreads();
  if (t < 64) {
    float M = pMq[t], L = pLq[t];   // q=0 always has valid col 0
#pragma unroll
    for (int q = 1; q < 4; ++q) {
      const float mq = pMq[q*64 + t], lq = pLq[q*64 + t];
      if (mq > -INFINITY) {
        const float mn = fmaxf(M, mq);
        L = L*__expf(M - mn) + lq*__expf(mq - mn);
        M = mn;
      }
    }
    pmE[t*1024 + tile] = M; plE[t*1024 + tile] = L;
  }
}

// ---------------------------------------------------------------------------
// Kernel E: per-row reduce of NTILE partials -> cvec[row]. One wave per row.
// ---------------------------------------------------------------------------
__global__ __launch_bounds__(256) void lsm_rowreduce(
    const float* __restrict__ pmE, const float* __restrict__ plE,
    float* __restrict__ cvec)
{
  const int t = threadIdx.x;
  const int w = t >> 6, lane = t & 63;
  const int row = blockIdx.x*4 + w;
  if (row >= BB) return;
  float M = -INFINITY, L = 0.f;
  for (int q = lane; q < NTILE; q += 64) {
    const float mq = pmE[row*1024 + q], lq = plE[row*1024 + q];
    const float mn = fmaxf(M, mq);
    L = L*__expf(M - mn) + lq*__expf(mq - mn);
    M = mn;
  }
#pragma unroll
  for (int off = 32; off >= 1; off >>= 1) {
    const float m2 = __shfl_xor(M, off, 64), l2 = __shfl_xor(L, off, 64);
    const float mn = fmaxf(M, m2);
    L = L*__expf(M - mn) + l2*__expf(m2 - mn);
    M = mn;
  }
  if (lane == 0) cvec[row] = M + logf(L);
}

// ---------------------------------------------------------------------------
// Kernel F: logits -= cvec[row].
// ---------------------------------------------------------------------------
__global__ __launch_bounds__(256) void lsm_sub(
    float* __restrict__ out, const float* __restrict__ cvec)
{
  const unsigned total4 = (unsigned)(BB*(unsigned)VV/4u);
  const unsigned idx = blockIdx.x*256u + threadIdx.x;
  if (idx >= total4) return;
  const unsigned i = idx*4u;
  float4 v = *(float4*)(out + i);
  v.x -= cvec[i/VV];
  v.y -= cvec[(i+1)/VV];
  v.z -= cvec[(i+2)/VV];
  v.w -= cvec[(i+3)/VV];
  *(float4*)(out + i) = v;
}

// ---------------------------------------------------------------------------
extern "C" void kernel_launch(void* const* d_in, const int* in_sizes, int n_in,
                              void* d_out, int out_size, void* d_ws, size_t ws_size,
                              hipStream_t stream)
{
  const int*   last_output = (const int*)d_in[0];
  const float* last_hidden = (const float*)d_in[1];
  const float* enc         = (const float*)d_in[2];
  const float* emb         = (const float*)d_in[3];
  const float* W_ih        = (const float*)d_in[4];
  const float* b_ih        = (const float*)d_in[5];
  const float* W_hh        = (const float*)d_in[6];
  const float* b_hh        = (const float*)d_in[7];
  const float* W_out       = (const float*)d_in[8];
  const float* b_out       = (const float*)d_in[9];
  float* out = (float*)d_out;

  __hip_bfloat16* featA = (__hip_bfloat16*)d_ws;            // 128 KB
  float* gates = (float*)((char*)d_ws + 131072);            // 12x64x1536 f32 = 4.7 MB
  float* pm   = gates + (size_t)12*BB*1536;                 // 2048
  float* pl   = pm + BB*NSPLIT;                             // 2048
  float* pmE  = pl + BB*NSPLIT;                             // 64*1024
  float* plE  = pmE + BB*1024;                              // 64*1024
  float* cvec = plE + BB*1024;                              // 64
  float* pacc = out;   // 4 MB parked in dead logits region
  float* hid_out = out + (size_t)BB*VV;

  attn_partial <<<dim3(BB*NSPLIT), dim3(256), 0, stream>>>(last_hidden, enc, pm, pl, pacc);
  attn_reduce  <<<dim3(BB),        dim3(256), 0, stream>>>(pm, pl, pacc, featA);
  gru_gemm     <<<dim3(24*12),     dim3(256), 0, stream>>>(last_output, emb, last_hidden,
                                                           featA, W_ih, W_hh, gates);
  gru_pointwise<<<dim3(BB),        dim3(512), 0, stream>>>(gates, last_hidden, b_ih, b_hh,
                                                           hid_out, featA);
  logits_gemm  <<<dim3(NTILE),     dim3(256), 0, stream>>>(featA, W_out, b_out, out, pmE, plE);
  lsm_rowreduce<<<dim3(16),        dim3(256), 0, stream>>>(pmE, plE, cvec);
  lsm_sub      <<<dim3((int)(((size_t)BB*VV/4 + 255)/256)), dim3(256), 0, stream>>>(out, cvec);
}